// Round 2
// baseline (222.257 us; speedup 1.0000x reference)
//
#include <hip/hip_runtime.h>
#include <stdint.h>

typedef __attribute__((ext_vector_type(8))) short bf16x8;
typedef __attribute__((ext_vector_type(4))) float f32x4;

#if __has_builtin(__builtin_amdgcn_exp2f)
#define EXP2F(x) __builtin_amdgcn_exp2f(x)
#else
#define EXP2F(x) exp2f(x)
#endif

__device__ __forceinline__ short f2bf(float f) {
    union { float f; uint32_t u; } c; c.f = f;
    return (short)((c.u + 0x7fffu + ((c.u >> 16) & 1u)) >> 16);
}

// async global->LDS 16B/lane: dest = wave-uniform base + lane*16 (m97/m104 semantics)
typedef __attribute__((address_space(1))) void gvoid;
typedef __attribute__((address_space(3))) void lvoid;
__device__ __forceinline__ void async_cp16(const void* g, void* l) {
    __builtin_amdgcn_global_load_lds((gvoid*)g, (lvoid*)l, 16, 0, 0);
}

// ---- prep: Wt2g chunk-major [16 kchunks][192 cols][32 k] bf16 (k-slot XOR-swizzled)
// LDS 8-short slot s of col c holds global k-slot s ^ (c&3)  (bank-conflict-free B reads)
__global__ void prep_kernel(const float* __restrict__ Wk, const float* __restrict__ bk,
                            const float* __restrict__ Wq, const float* __restrict__ bq,
                            const float* __restrict__ Wv, const float* __restrict__ bv,
                            short* __restrict__ Wt2g, float* __restrict__ bcat) {
    const int col = blockIdx.x;  // 0..191 (0-63=K, 64-127=Q, 128-191=V)
    const float* W; const float* bb; int c0;
    if (col < 64)       { W = Wk; bb = bk; c0 = col; }
    else if (col < 128) { W = Wq; bb = bq; c0 = col - 64; }
    else                { W = Wv; bb = bv; c0 = col - 128; }
    for (int c = threadIdx.x; c < 512; c += blockDim.x) {
        const int k5 = c & 31;
        Wt2g[(c >> 5) * 6144 + col * 32 + ((((k5 >> 3) ^ (col & 3)) << 3)) + (k5 & 7)] =
            f2bf(W[(size_t)c * 64 + c0]);
    }
    if (threadIdx.x == 0) bcat[col] = bb[c0];
}

// ---- fused per-batch kernel, 1024 threads = 16 waves ----
// Phase 1 (QKV projection), 4x4 wave grid, DEEP-PIPELINED (T3+T4):
//   3 LDS buffers, counted s_waitcnt vmcnt(N) + raw s_barrier -> loads for
//   chunks kc+1,kc+2 stay in flight across barriers (never drained to 0 in
//   the main loop). x staged fp32 direct via global_load_lds (no reg trip);
//   source-side 3-bit XOR slot swizzle gives conflict-free ds_read_b128.
//   Per-wave loads/chunk: waves 0-11: 2x + 1W = 3; waves 12-15: 2.
// Phase 2: all-LDS causal attention; q-tile = magic-square perm of wave.
// LDS (dynamic, 135168 B):
//   phase 1: xs[d] @ d*32768 (d=0..2, fp32) | ws[d] @ 98304 + d*12288
//   phase 2: Ks @0 (32K) | Qs @32768 | Vts @65536 (32K) | Ps @98304 (20K)
#define PSTR 40

__global__ __launch_bounds__(1024, 4) void fused_kernel(
    const float* __restrict__ x, const short* __restrict__ Wt2g,
    const float* __restrict__ bcat, float* __restrict__ out) {
    extern __shared__ __align__(16) char smem[];

    const int tid = threadIdx.x;
    const int wave = tid >> 6, lane = tid & 63;
    const int quad = lane >> 4, l16 = lane & 15;
    const int b = blockIdx.x;
    const int rg = wave >> 2, cg = wave & 3;

    // ================= phase 1: QKV projection =================
    f32x4 acc[4][3];
#pragma unroll
    for (int m = 0; m < 4; m++)
#pragma unroll
        for (int j = 0; j < 3; j++) acc[m][j] = (f32x4){0.f, 0.f, 0.f, 0.f};

    const float* xsrc = x + (size_t)b * 256 * 512;
    const int xr = lane >> 3, xsl = lane & 7;           // x granule row / 16B slot
    const int bsw = (quad ^ (l16 & 3)) << 3;            // B-frag slot (shorts)
    const int xq0 = ((2 * quad) ^ (l16 & 7)) << 2;      // A-frag slot0 (floats)
    const int xq1 = ((2 * quad + 1) ^ (l16 & 7)) << 2;  // A-frag slot1 (floats)

#define XS(d) (smem + (d) * 32768)
#define WSB(d) (smem + 98304 + (d) * 12288)
// x granule i = rows 8i..8i+7 x 128B; LDS slot xsl holds global slot xsl^(row&7)
#define STAGE(kc, d)                                                                     \
    {                                                                                    \
        async_cp16(xsrc + (size_t)(wave * 8 + xr) * 512 + (kc) * 32 + ((xsl ^ xr) << 2), \
                   XS(d) + wave * 1024);                                                 \
        async_cp16(xsrc + (size_t)((wave + 16) * 8 + xr) * 512 + (kc) * 32 +             \
                       ((xsl ^ xr) << 2),                                                \
                   XS(d) + (wave + 16) * 1024);                                          \
        if (wave < 12)                                                                   \
            async_cp16(Wt2g + (size_t)(kc) * 6144 + wave * 512 + lane * 8,               \
                       WSB(d) + wave * 1024);                                            \
    }
#define FENCE() asm volatile("" ::: "memory")

    auto COMPUTE = [&](int d) {
        const short* wb = (const short*)WSB(d);
        bf16x8 bf0 = *(const bf16x8*)&wb[(cg * 48 + l16) * 32 + bsw];
        bf16x8 bf1 = *(const bf16x8*)&wb[(cg * 48 + 16 + l16) * 32 + bsw];
        bf16x8 bf2 = *(const bf16x8*)&wb[(cg * 48 + 32 + l16) * 32 + bsw];
        const float* xb = (const float*)XS(d);
        const int rbase = (rg * 64 + l16) * 32;
#pragma unroll
        for (int m = 0; m < 4; m++) {
            f32x4 u0 = *(const f32x4*)&xb[rbase + m * 512 + xq0];
            f32x4 u1 = *(const f32x4*)&xb[rbase + m * 512 + xq1];
            bf16x8 a;
#pragma unroll
            for (int i = 0; i < 4; i++) { a[i] = f2bf(u0[i]); a[4 + i] = f2bf(u1[i]); }
            acc[m][0] = __builtin_amdgcn_mfma_f32_16x16x32_bf16(a, bf0, acc[m][0], 0, 0, 0);
            acc[m][1] = __builtin_amdgcn_mfma_f32_16x16x32_bf16(a, bf1, acc[m][1], 0, 0, 0);
            acc[m][2] = __builtin_amdgcn_mfma_f32_16x16x32_bf16(a, bf2, acc[m][2], 0, 0, 0);
        }
    };

    // prologue: 3 chunks in flight
    STAGE(0, 0) STAGE(1, 1) STAGE(2, 2)

    for (int kc = 0; kc < 14; ++kc) {
        const int d = kc % 3;
        // my chunk-kc loads done (2 newer chunks stay in flight)
        if (wave < 12) asm volatile("s_waitcnt vmcnt(6)" ::: "memory");
        else           asm volatile("s_waitcnt vmcnt(4)" ::: "memory");
        __builtin_amdgcn_s_barrier();   // everyone's chunk-kc loads done
        FENCE();
        COMPUTE(d);
        __builtin_amdgcn_s_barrier();   // everyone done reading buf d
        FENCE();
        if (kc < 13) STAGE(kc + 3, d)
    }
    // kc = 14: chunks 14,15 in flight
    if (wave < 12) asm volatile("s_waitcnt vmcnt(3)" ::: "memory");
    else           asm volatile("s_waitcnt vmcnt(2)" ::: "memory");
    __builtin_amdgcn_s_barrier();
    FENCE();
    COMPUTE(2);
    // kc = 15
    asm volatile("s_waitcnt vmcnt(0)" ::: "memory");
    __builtin_amdgcn_s_barrier();
    FENCE();
    COMPUTE(0);
    __syncthreads();   // all phase-1 LDS reads done before epilogue overwrites

    // ---- epilogue: C-layout (row=quad*4+r, col=l16) -> swizzled phase-2 LDS ----
    short* Ks  = (short*)smem;
    short* Qs  = (short*)(smem + 32768);
    short* Vts = (short*)(smem + 65536);
    short* Ps  = (short*)(smem + 98304);
#pragma unroll
    for (int j = 0; j < 3; j++) {
        const int col = cg * 48 + j * 16 + l16;
        const float bias = bcat[col];
        const int h = col & 63;
        const int sel = col >> 6;  // wave-uniform per j (base multiple of 16)
#pragma unroll
        for (int m = 0; m < 4; m++) {
#pragma unroll
            for (int r = 0; r < 4; r++) {
                const short v = f2bf(acc[m][j][r] + bias);
                const int row = rg * 64 + m * 16 + quad * 4 + r;
                if (sel == 0)
                    Ks[row * 64 + (((h >> 3) ^ (row & 7)) << 3) + (h & 7)] = v;
                else if (sel == 1)
                    Qs[row * 64 + (((h >> 3) ^ (row & 7)) << 3) + (h & 7)] = v;
                else
                    Vts[h * 256 + (((row >> 3) ^ (h & 7)) << 3) + (row & 7)] = v;
            }
        }
    }
    __syncthreads();

    // ================= phase 2: causal attention, all-LDS =================
    // q-tile = magic-square permutation of wave: SIMD s = w&3 gets tiles
    // {s^0, 4+(s^1), 8+(s^2), 12+(s^3)} -> per-SIMD causal work equalized.
    const int qt = ((wave >> 2) << 2) | ((wave & 3) ^ (wave >> 2));
    const float sc2 = 0.125f * 1.44269504088896340736f;  // 1/sqrt(64) * log2(e)
    short* myP = Ps + wave * (16 * PSTR);

    const int qrow = qt * 16 + l16;
    const int sw = l16 & 7;
    bf16x8 qf0 = *(const bf16x8*)&Qs[qrow * 64 + ((quad ^ sw) << 3)];
    bf16x8 qf1 = *(const bf16x8*)&Qs[qrow * 64 + (((4 + quad) ^ sw) << 3)];

    f32x4 St[16];
#pragma unroll
    for (int i = 0; i < 16; i++) St[i] = (f32x4){0.f, 0.f, 0.f, 0.f};
#pragma unroll
    for (int nt = 0; nt < 16; nt++) if (nt <= qt) {
        const int krow = nt * 16 + l16;
        bf16x8 kf0 = *(const bf16x8*)&Ks[krow * 64 + ((quad ^ sw) << 3)];
        bf16x8 kf1 = *(const bf16x8*)&Ks[krow * 64 + (((4 + quad) ^ sw) << 3)];
        St[nt] = __builtin_amdgcn_mfma_f32_16x16x32_bf16(qf0, kf0, St[nt], 0, 0, 0);
        St[nt] = __builtin_amdgcn_mfma_f32_16x16x32_bf16(qf1, kf1, St[nt], 0, 0, 0);
    }

    // mask + base-2 softmax; C-layout rows = quad*4+r, col = l16
    const int rowq = qt * 16 + quad * 4;
    float mx[4], ls[4];
#pragma unroll
    for (int r = 0; r < 4; r++) mx[r] = -3.0e38f;
#pragma unroll
    for (int nt = 0; nt < 16; nt++) if (nt <= qt) {
        const int cs = nt * 16 + l16;
#pragma unroll
        for (int r = 0; r < 4; r++) {
            float s = (cs <= rowq + r) ? St[nt][r] * sc2 : -3.0e38f;
            St[nt][r] = s;
            mx[r] = fmaxf(mx[r], s);
        }
    }
#pragma unroll
    for (int d = 1; d < 16; d <<= 1)
#pragma unroll
        for (int r = 0; r < 4; r++)
            mx[r] = fmaxf(mx[r], __shfl_xor(mx[r], d, 64));
#pragma unroll
    for (int r = 0; r < 4; r++) ls[r] = 0.f;
#pragma unroll
    for (int nt = 0; nt < 16; nt++) if (nt <= qt) {
#pragma unroll
        for (int r = 0; r < 4; r++) {
            float p = EXP2F(St[nt][r] - mx[r]);
            St[nt][r] = p;                 // St[nt>qt] stays 0 == correct P
            ls[r] += p;
        }
    }
#pragma unroll
    for (int d = 1; d < 16; d <<= 1)
#pragma unroll
        for (int r = 0; r < 4; r++)
            ls[r] += __shfl_xor(ls[r], d, 64);

    // O = P V over 32-s chunks; P via wave-local LDS C->A roundtrip
    f32x4 O[4];
#pragma unroll
    for (int i = 0; i < 4; i++) O[i] = (f32x4){0.f, 0.f, 0.f, 0.f};
    const int nch = (qt + 2) >> 1;         // ceil((qt+1)/2), wave-uniform
#pragma unroll
    for (int c2 = 0; c2 < 8; c2++) if (c2 < nch) {
#pragma unroll
        for (int t2i = 0; t2i < 2; t2i++) {
            const int nt = c2 * 2 + t2i;   // St[nt]=0 beyond diagonal => P=0
#pragma unroll
            for (int r = 0; r < 4; r++)
                myP[(quad * 4 + r) * PSTR + t2i * 16 + l16] = f2bf(St[nt][r]);
        }
        bf16x8 pf = *(const bf16x8*)&myP[l16 * PSTR + quad * 8];
#pragma unroll
        for (int ht = 0; ht < 4; ht++) {
            const int h = ht * 16 + l16;
            bf16x8 vf = *(const bf16x8*)&Vts[h * 256 + (((c2 * 4 + quad) ^ (h & 7)) << 3)];
            O[ht] = __builtin_amdgcn_mfma_f32_16x16x32_bf16(pf, vf, O[ht], 0, 0, 0);
        }
    }

    float rls[4];
#pragma unroll
    for (int r = 0; r < 4; r++) rls[r] = 1.0f / ls[r];
#pragma unroll
    for (int ht = 0; ht < 4; ht++)
#pragma unroll
        for (int r = 0; r < 4; r++)
            out[((size_t)b * 256 + rowq + r) * 64 + ht * 16 + l16] = O[ht][r] * rls[r];
#undef STAGE
#undef XS
#undef WSB
#undef FENCE
}

extern "C" void kernel_launch(void* const* d_in, const int* in_sizes, int n_in,
                              void* d_out, int out_size, void* d_ws, size_t ws_size,
                              hipStream_t stream) {
    const float* x  = (const float*)d_in[0];
    const float* Wk = (const float*)d_in[1];
    const float* bk = (const float*)d_in[2];
    const float* Wq = (const float*)d_in[3];
    const float* bq = (const float*)d_in[4];
    const float* Wv = (const float*)d_in[5];
    const float* bv = (const float*)d_in[6];
    float* out = (float*)d_out;

    char* ws = (char*)d_ws;
    short* Wt2g = (short*)(ws);             // 196608 B (chunk-major)
    float* bcat = (float*)(ws + 196608);    // 768 B

    const int smem_bytes = 135168;          // 3x(32K x + 12K W); phase 2 needs 118784
    (void)hipFuncSetAttribute((const void*)fused_kernel,
                              hipFuncAttributeMaxDynamicSharedMemorySize, smem_bytes);

    prep_kernel<<<192, 256, 0, stream>>>(Wk, bk, Wq, bq, Wv, bv, Wt2g, bcat);
    fused_kernel<<<256, 1024, smem_bytes, stream>>>(x, Wt2g, bcat, out);
}